// Round 3
// baseline (288.269 us; speedup 1.0000x reference)
//
#include <hip/hip_runtime.h>
#include <hip/hip_bf16.h>
#include <cstdint>
#include <cstddef>

// Problem constants
#define B_   64
#define LC_  1024
#define LQ_  128
#define D_   128

typedef __bf16 bf16;
typedef bf16  bf16x8 __attribute__((ext_vector_type(8)));
typedef bf16  bf16x4 __attribute__((ext_vector_type(4)));
typedef float f32x4  __attribute__((ext_vector_type(4)));

__device__ __forceinline__ f32x4 mfma16(bf16x8 a, bf16x8 b, f32x4 c) {
  return __builtin_amdgcn_mfma_f32_16x16x32_bf16(a, b, c, 0, 0, 0);
}

// ---------------------------------------------------------------------------
// K0 (merged): blockIdx.x<8 -> c-slice prep: cw1 = c.w1, cw3 = bf16(c*w3),
//              cT = bf16(c)^T ;  blockIdx.x==8 -> q prep: qw2, qb, qT.
// ---------------------------------------------------------------------------
__global__ __launch_bounds__(256) void k0(const float* __restrict__ c, const float* __restrict__ q,
                                          const float* __restrict__ w,
                                          float* __restrict__ cw1, float* __restrict__ qw2,
                                          bf16* __restrict__ cw3, bf16* __restrict__ cT,
                                          bf16* __restrict__ qb, bf16* __restrict__ qT) {
  __shared__ float wbuf[256];
  __shared__ bf16  tile[128 * 132];
  const int b = blockIdx.y;
  const int t = threadIdx.x;
  if (blockIdx.x < 8) {
    const int k0 = blockIdx.x * 128;
    if (t < 128) { wbuf[t] = w[t]; wbuf[128 + t] = w[256 + t]; }
    __syncthreads();
    {
      const int r = t >> 1, d0 = (t & 1) * 64;
      const float* crow = c + ((size_t)(b * LC_ + k0 + r) * D_ + d0);
      bf16* orow = cw3 + ((size_t)(b * LC_ + k0 + r) * D_ + d0);
      float dot = 0.f;
#pragma unroll
      for (int v = 0; v < 8; ++v) {
        const float4 f0 = ((const float4*)crow)[v * 2 + 0];
        const float4 f1 = ((const float4*)crow)[v * 2 + 1];
        const int dd = d0 + v * 8;
        dot += f0.x * wbuf[dd + 0] + f0.y * wbuf[dd + 1] + f0.z * wbuf[dd + 2] + f0.w * wbuf[dd + 3]
             + f1.x * wbuf[dd + 4] + f1.y * wbuf[dd + 5] + f1.z * wbuf[dd + 6] + f1.w * wbuf[dd + 7];
        bf16* cr = &tile[r * 132 + dd];
        cr[0] = (bf16)f0.x; cr[1] = (bf16)f0.y; cr[2] = (bf16)f0.z; cr[3] = (bf16)f0.w;
        cr[4] = (bf16)f1.x; cr[5] = (bf16)f1.y; cr[6] = (bf16)f1.z; cr[7] = (bf16)f1.w;
        bf16x8 o;
        o[0] = (bf16)(f0.x * wbuf[128 + dd + 0]); o[1] = (bf16)(f0.y * wbuf[128 + dd + 1]);
        o[2] = (bf16)(f0.z * wbuf[128 + dd + 2]); o[3] = (bf16)(f0.w * wbuf[128 + dd + 3]);
        o[4] = (bf16)(f1.x * wbuf[128 + dd + 4]); o[5] = (bf16)(f1.y * wbuf[128 + dd + 5]);
        o[6] = (bf16)(f1.z * wbuf[128 + dd + 6]); o[7] = (bf16)(f1.w * wbuf[128 + dd + 7]);
        *(bf16x8*)(orow + v * 8) = o;
      }
      dot += __shfl_xor(dot, 1);
      if ((t & 1) == 0) cw1[b * LC_ + k0 + r] = dot;
    }
    __syncthreads();
    {
      const int d = t >> 1, kh = (t & 1) * 64;
      bf16* trow = cT + ((size_t)(b * D_ + d) * LC_ + k0 + kh);
#pragma unroll
      for (int v = 0; v < 8; ++v) {
        bf16x8 o;
#pragma unroll
        for (int e = 0; e < 8; ++e) o[e] = tile[(kh + v * 8 + e) * 132 + d];
        *(bf16x8*)(trow + v * 8) = o;
      }
    }
  } else {
    if (t < 128) wbuf[t] = w[128 + t];
    __syncthreads();
    {
      const int r = t >> 1, d0 = (t & 1) * 64;
      const float* qrow = q + ((size_t)(b * LQ_ + r) * D_ + d0);
      bf16* orow = qb + ((size_t)(b * LQ_ + r) * D_ + d0);
      float dot = 0.f;
#pragma unroll
      for (int v = 0; v < 8; ++v) {
        const float4 f0 = ((const float4*)qrow)[v * 2 + 0];
        const float4 f1 = ((const float4*)qrow)[v * 2 + 1];
        const int dd = d0 + v * 8;
        dot += f0.x * wbuf[dd + 0] + f0.y * wbuf[dd + 1] + f0.z * wbuf[dd + 2] + f0.w * wbuf[dd + 3]
             + f1.x * wbuf[dd + 4] + f1.y * wbuf[dd + 5] + f1.z * wbuf[dd + 6] + f1.w * wbuf[dd + 7];
        bf16x8 o;
        o[0] = (bf16)f0.x; o[1] = (bf16)f0.y; o[2] = (bf16)f0.z; o[3] = (bf16)f0.w;
        o[4] = (bf16)f1.x; o[5] = (bf16)f1.y; o[6] = (bf16)f1.z; o[7] = (bf16)f1.w;
        bf16* qr = &tile[r * 132 + dd];
#pragma unroll
        for (int e = 0; e < 8; ++e) qr[e] = o[e];
        *(bf16x8*)(orow + v * 8) = o;
      }
      dot += __shfl_xor(dot, 1);
      if ((t & 1) == 0) qw2[b * LQ_ + r] = dot;
    }
    __syncthreads();
    {
      const int d = t >> 1, jh = (t & 1) * 64;
      bf16* trow = qT + ((size_t)(b * D_ + d) * LQ_ + jh);
#pragma unroll
      for (int v = 0; v < 8; ++v) {
        bf16x8 o;
#pragma unroll
        for (int e = 0; e < 8; ++e) o[e] = tile[(jh + v * 8 + e) * 132 + d];
        *(bf16x8*)(trow + v * 8) = o;
      }
    }
  }
}

// ---------------------------------------------------------------------------
// K1p: per (b, k-quarter ks, 32-wide j-slice): partial column-softmax sums.
//   Tpart[(b,ks,js)][j][d] = sum_{k in quarter} P[k,j] c[k,d]  (fp32)
//   lpart[(b,ks)][j]       = sum_{k in quarter} P[k,j]
// No big LDS: A/B frags straight from global; q B-frags hoisted to registers.
// ---------------------------------------------------------------------------
__global__ __launch_bounds__(256, 4) void k1p(const float* __restrict__ cw1, const float* __restrict__ qw2,
                                              const int* __restrict__ cmask,
                                              const bf16* __restrict__ cw3, const bf16* __restrict__ cT,
                                              const bf16* __restrict__ qb,
                                              float* __restrict__ Tpart, float* __restrict__ lpart) {
  __shared__ bf16  PT[32 * 72];      // [j][k]
  __shared__ float lred[4][32];
  const int bx = blockIdx.x;
  const int ks = bx >> 2, js = bx & 3;
  const int b = blockIdx.y;
  const int j0 = js * 32;
  const int t = threadIdx.x;
  const int w = t >> 6, lane = t & 63, quad = lane >> 4, l15 = lane & 15;

  // hoisted q-side B-frags (invariant over kt)
  bf16x8 bq[4][2];
#pragma unroll
  for (int kk = 0; kk < 4; ++kk) {
    bq[kk][0] = *(const bf16x8*)(qb + ((size_t)(b * LQ_ + j0 + l15) * D_ + kk * 32 + quad * 8));
    bq[kk][1] = *(const bf16x8*)(qb + ((size_t)(b * LQ_ + j0 + 16 + l15) * D_ + kk * 32 + quad * 8));
  }
  const float qv0 = qw2[b * LQ_ + j0 + l15];
  const float qv1 = qw2[b * LQ_ + j0 + 16 + l15];
  const f32x4 z = {0.f, 0.f, 0.f, 0.f};
  f32x4 Tacc[2][2] = {{z, z}, {z, z}};
  float lacc0 = 0.f, lacc1 = 0.f;

  for (int kt = 0; kt < 4; ++kt) {
    const int k0g = ks * 256 + kt * 64;
    // GEMM1: S tile, wave owns k-rows [w*16, w*16+16) x 32 j; A straight from global
    f32x4 S0 = z, S1 = z;
#pragma unroll
    for (int kk = 0; kk < 4; ++kk) {
      bf16x8 a = *(const bf16x8*)(cw3 + ((size_t)(b * LC_ + k0g + w * 16 + l15) * D_ + kk * 32 + quad * 8));
      S0 = mfma16(a, bq[kk][0], S0);
      S1 = mfma16(a, bq[kk][1], S1);
    }
    bf16x4 pk0, pk1;
#pragma unroll
    for (int rr = 0; rr < 4; ++rr) {
      const int krow = k0g + w * 16 + quad * 4 + rr;
      const float c1 = cw1[b * LC_ + krow];
      const int   cm = cmask[b * LC_ + krow];
      const float p0 = cm ? 0.f : __expf(S0[rr] + c1 + qv0);
      const float p1 = cm ? 0.f : __expf(S1[rr] + c1 + qv1);
      lacc0 += p0; lacc1 += p1;
      pk0[rr] = (bf16)p0; pk1[rr] = (bf16)p1;
    }
    *(bf16x4*)&PT[l15 * 72 + w * 16 + quad * 4] = pk0;
    *(bf16x4*)&PT[(16 + l15) * 72 + w * 16 + quad * 4] = pk1;
    __syncthreads();

    // GEMM2: Tpart[j, d-slice] += P^T @ c ; wave owns d in [w*32, w*32+32);
    // B (cT rows) straight from global.
#pragma unroll
    for (int kk = 0; kk < 2; ++kk) {
      bf16x8 a0 = *(bf16x8*)&PT[l15 * 72 + kk * 32 + quad * 8];
      bf16x8 a1 = *(bf16x8*)&PT[(16 + l15) * 72 + kk * 32 + quad * 8];
      bf16x8 b0 = *(const bf16x8*)(cT + ((size_t)(b * D_ + w * 32 + l15) * LC_ + k0g + kk * 32 + quad * 8));
      bf16x8 b1 = *(const bf16x8*)(cT + ((size_t)(b * D_ + w * 32 + 16 + l15) * LC_ + k0g + kk * 32 + quad * 8));
      Tacc[0][0] = mfma16(a0, b0, Tacc[0][0]);
      Tacc[0][1] = mfma16(a0, b1, Tacc[0][1]);
      Tacc[1][0] = mfma16(a1, b0, Tacc[1][0]);
      Tacc[1][1] = mfma16(a1, b1, Tacc[1][1]);
    }
    __syncthreads();
  }

  // partial l_j: quad-reduce in-wave, then cross-wave via LDS
  lacc0 += __shfl_xor(lacc0, 16); lacc0 += __shfl_xor(lacc0, 32);
  lacc1 += __shfl_xor(lacc1, 16); lacc1 += __shfl_xor(lacc1, 32);
  if (lane < 16) { lred[w][l15] = lacc0; lred[w][16 + l15] = lacc1; }
  __syncthreads();
  if (t < 32)
    lpart[(size_t)(b * 4 + ks) * 128 + j0 + t] = lred[0][t] + lred[1][t] + lred[2][t] + lred[3][t];

  // fp32 partial T tile [32 j][128 d]
  float* tp = Tpart + ((size_t)((b * 4 + ks) * 4 + js)) * (32 * 128);
#pragma unroll
  for (int mt = 0; mt < 2; ++mt)
#pragma unroll
    for (int nt = 0; nt < 2; ++nt)
#pragma unroll
      for (int rr = 0; rr < 4; ++rr)
        tp[(mt * 16 + quad * 4 + rr) * 128 + w * 32 + nt * 16 + l15] = Tacc[mt][nt][rr];
}

// ---------------------------------------------------------------------------
// K1r: reduce the four k-quarters, normalize by l_j, emit TT = bf16(T)^T [d][j]
// ---------------------------------------------------------------------------
__global__ __launch_bounds__(256) void k1r(const float* __restrict__ Tpart,
                                           const float* __restrict__ lpart,
                                           bf16* __restrict__ TT) {
  __shared__ float Tsum[32 * 132];
  __shared__ float linv[32];
  const int js = blockIdx.x, b = blockIdx.y;
  const int j0 = js * 32;
  const int t = threadIdx.x;
  const float4* p0 = (const float4*)(Tpart + ((size_t)((b * 4 + 0) * 4 + js)) * (32 * 128));
  const float4* p1 = (const float4*)(Tpart + ((size_t)((b * 4 + 1) * 4 + js)) * (32 * 128));
  const float4* p2 = (const float4*)(Tpart + ((size_t)((b * 4 + 2) * 4 + js)) * (32 * 128));
  const float4* p3 = (const float4*)(Tpart + ((size_t)((b * 4 + 3) * 4 + js)) * (32 * 128));
#pragma unroll
  for (int idx = t; idx < 1024; idx += 256) {
    const int row = idx >> 5, seg = idx & 31;
    const float4 v0 = p0[idx];
    const float4 v1 = p1[idx];
    const float4 v2 = p2[idx];
    const float4 v3 = p3[idx];
    float4 s;
    s.x = (v0.x + v1.x) + (v2.x + v3.x);
    s.y = (v0.y + v1.y) + (v2.y + v3.y);
    s.z = (v0.z + v1.z) + (v2.z + v3.z);
    s.w = (v0.w + v1.w) + (v2.w + v3.w);
    *(float4*)&Tsum[row * 132 + seg * 4] = s;
  }
  if (t < 32)
    linv[t] = 1.f / (lpart[(size_t)(b * 4 + 0) * 128 + j0 + t] +
                     lpart[(size_t)(b * 4 + 1) * 128 + j0 + t] +
                     lpart[(size_t)(b * 4 + 2) * 128 + j0 + t] +
                     lpart[(size_t)(b * 4 + 3) * 128 + j0 + t]);
  __syncthreads();
  const int d = t >> 1, jh = (t & 1) * 16;
  bf16x8 o0, o1;
#pragma unroll
  for (int e = 0; e < 8; ++e) {
    o0[e] = (bf16)(Tsum[(jh + e) * 132 + d] * linv[jh + e]);
    o1[e] = (bf16)(Tsum[(jh + 8 + e) * 132 + d] * linv[jh + 8 + e]);
  }
  bf16* dst = TT + ((size_t)(b * D_ + d) * LQ_ + j0 + jh);
  *(bf16x8*)dst = o0;
  *(bf16x8*)(dst + 8) = o1;
}

// ---------------------------------------------------------------------------
// K2: per (b, 64-row i-tile): row softmax (mask=q_mask on j), A = S1@q,
//     Batt = S1@T ; write [c | A | c*A | c*Batt]. A-frags + biases hoisted to
//     registers; all B-frags straight from global; LDS only for the P1
//     transpose and the fp32 epilogue staging (union).
// ---------------------------------------------------------------------------
__global__ __launch_bounds__(256, 4) void k2(const float* __restrict__ c, const float* __restrict__ cw1,
                                             const float* __restrict__ qw2, const int* __restrict__ qmask,
                                             const bf16* __restrict__ cw3, const bf16* __restrict__ qb,
                                             const bf16* __restrict__ qT, const bf16* __restrict__ TT,
                                             float* __restrict__ out) {
  __shared__ __align__(16) char smem[33792];
  bf16*  P1  = (bf16*)smem;             // [64][40] loop phase
  float* A32 = (float*)smem;            // [32][132] epilogue
  float* B32 = (float*)(smem + 16896);  // [32][132] epilogue
  const int it = blockIdx.x, b = blockIdx.y;
  const int i0 = it * 64;
  const int t = threadIdx.x;
  const int w = t >> 6, lane = t & 63, quad = lane >> 4, l15 = lane & 15;

  // hoisted A-frags (cw3 i-rows) and row biases, invariant over jt
  bf16x8 af[4];
#pragma unroll
  for (int kk = 0; kk < 4; ++kk)
    af[kk] = *(const bf16x8*)(cw3 + ((size_t)(b * LC_ + i0 + w * 16 + l15) * D_ + kk * 32 + quad * 8));
  float c1r[4];
#pragma unroll
  for (int rr = 0; rr < 4; ++rr)
    c1r[rr] = cw1[b * LC_ + i0 + w * 16 + quad * 4 + rr];

  const f32x4 z = {0.f, 0.f, 0.f, 0.f};
  f32x4 Aacc[8], Bacc[8];
#pragma unroll
  for (int n = 0; n < 8; ++n) { Aacc[n] = z; Bacc[n] = z; }
  float lacc[4] = {0.f, 0.f, 0.f, 0.f};

  for (int jt = 0; jt < 4; ++jt) {
    const int j0 = jt * 32;
    // GEMM1: S tile; B (q rows) straight from global
    f32x4 S0 = z, S1 = z;
#pragma unroll
    for (int kk = 0; kk < 4; ++kk) {
      bf16x8 b0 = *(const bf16x8*)(qb + ((size_t)(b * LQ_ + j0 + l15) * D_ + kk * 32 + quad * 8));
      bf16x8 b1 = *(const bf16x8*)(qb + ((size_t)(b * LQ_ + j0 + 16 + l15) * D_ + kk * 32 + quad * 8));
      S0 = mfma16(af[kk], b0, S0);
      S1 = mfma16(af[kk], b1, S1);
    }
    const float qv0 = qw2[b * LQ_ + j0 + l15];
    const float qv1 = qw2[b * LQ_ + j0 + 16 + l15];
    const int   qm0 = qmask[b * LQ_ + j0 + l15];
    const int   qm1 = qmask[b * LQ_ + j0 + 16 + l15];
#pragma unroll
    for (int rr = 0; rr < 4; ++rr) {
      const float p0 = qm0 ? 0.f : __expf(S0[rr] + c1r[rr] + qv0);
      const float p1 = qm1 ? 0.f : __expf(S1[rr] + c1r[rr] + qv1);
      lacc[rr] += p0 + p1;
      P1[(w * 16 + quad * 4 + rr) * 40 + l15] = (bf16)p0;
      P1[(w * 16 + quad * 4 + rr) * 40 + 16 + l15] = (bf16)p1;
    }
    __syncthreads();

    // GEMM2/3: one A-frag (P1) reused for 16 MFMAs; B straight from global
    bf16x8 aP = *(bf16x8*)&P1[(w * 16 + l15) * 40 + quad * 8];
#pragma unroll
    for (int nt = 0; nt < 8; ++nt) {
      bf16x8 bq2 = *(const bf16x8*)(qT + ((size_t)(b * D_ + nt * 16 + l15) * LQ_ + j0 + quad * 8));
      bf16x8 bt2 = *(const bf16x8*)(TT + ((size_t)(b * D_ + nt * 16 + l15) * LQ_ + j0 + quad * 8));
      Aacc[nt] = mfma16(aP, bq2, Aacc[nt]);
      Bacc[nt] = mfma16(aP, bt2, Bacc[nt]);
    }
    __syncthreads();
  }

  // l_i inverse: butterfly over the 16 j-lanes
#pragma unroll
  for (int rr = 0; rr < 4; ++rr) {
    float v = lacc[rr];
    v += __shfl_xor(v, 1); v += __shfl_xor(v, 2);
    v += __shfl_xor(v, 4); v += __shfl_xor(v, 8);
    lacc[rr] = 1.f / v;
  }

  // epilogue: two 32-row passes; stage A,B fp32 in LDS, fused float4 writes
#pragma unroll
  for (int h = 0; h < 2; ++h) {
    if ((w >> 1) == h) {
      const int lrow0 = (w & 1) * 16 + quad * 4;
#pragma unroll
      for (int nt = 0; nt < 8; ++nt)
#pragma unroll
        for (int rr = 0; rr < 4; ++rr) {
          A32[(lrow0 + rr) * 132 + nt * 16 + l15] = Aacc[nt][rr] * lacc[rr];
          B32[(lrow0 + rr) * 132 + nt * 16 + l15] = Bacc[nt][rr] * lacc[rr];
        }
    }
    __syncthreads();
#pragma unroll
    for (int idx = t; idx < 1024; idx += 256) {
      const int lrow = idx >> 5, seg = idx & 31;
      const size_t grow = (size_t)(b * LC_ + i0 + h * 32 + lrow);
      const float4 c4 = ((const float4*)(c + grow * D_))[seg];
      const float4 a4 = *(float4*)&A32[lrow * 132 + seg * 4];
      const float4 b4 = *(float4*)&B32[lrow * 132 + seg * 4];
      float4* ob = (float4*)(out + grow * 512);
      ob[seg] = c4;
      ob[32 + seg] = a4;
      float4 ca; ca.x = c4.x * a4.x; ca.y = c4.y * a4.y; ca.z = c4.z * a4.z; ca.w = c4.w * a4.w;
      ob[64 + seg] = ca;
      float4 cb; cb.x = c4.x * b4.x; cb.y = c4.y * b4.y; cb.z = c4.z * b4.z; cb.w = c4.w * b4.w;
      ob[96 + seg] = cb;
    }
    __syncthreads();
  }
}

// ---------------------------------------------------------------------------
extern "C" void kernel_launch(void* const* d_in, const int* in_sizes, int n_in,
                              void* d_out, int out_size, void* d_ws, size_t ws_size,
                              hipStream_t stream) {
  (void)in_sizes; (void)n_in; (void)out_size; (void)ws_size;
  const float* c     = (const float*)d_in[0];
  const float* q     = (const float*)d_in[1];
  const int*   cmask = (const int*)d_in[2];
  const int*   qmask = (const int*)d_in[3];
  const float* w     = (const float*)d_in[4];
  float* out = (float*)d_out;

  // workspace layout (40.1 MB)
  char* ws = (char*)d_ws;
  float* cw1 = (float*)(ws + 0);          //  64*1024 f32
  float* qw2 = (float*)(ws + 262144);     //  64*128  f32
  bf16*  cw3 = (bf16*)(ws + 294912);      //  64*1024*128 bf16  (c*w3)
  bf16*  cT  = (bf16*)(ws + 17072128);    //  64*128*1024 bf16  (c transposed)
  bf16*  qb  = (bf16*)(ws + 33849344);    //  64*128*128 bf16
  bf16*  qT  = (bf16*)(ws + 35946496);    //  64*128*128 bf16  (q transposed)
  bf16*  TT  = (bf16*)(ws + 38043648);    //  64*128*128 bf16  (T transposed)

  // k-split partials live in d_out scratch (fully overwritten by k2 afterwards)
  float* Tpart = out;                     //  64*4*4*32*128 f32 = 16.8 MB
  float* lpart = out + 4194304;           //  64*4*128 f32

  k0 <<<dim3(9, 64), 256, 0, stream>>>(c, q, w, cw1, qw2, cw3, cT, qb, qT);
  k1p<<<dim3(16, 64), 256, 0, stream>>>(cw1, qw2, cmask, cw3, cT, qb, Tpart, lpart);
  k1r<<<dim3(4, 64), 256, 0, stream>>>(Tpart, lpart, TT);
  k2 <<<dim3(16, 64), 256, 0, stream>>>(c, cw1, qw2, qmask, cw3, qb, qT, TT, out);
}